// Round 5
// baseline (437.377 us; speedup 1.0000x reference)
//
#include <hip/hip_runtime.h>

#define N_NODES 50000
#define N_EDGES 1600000
#define D_FEAT 32
#define SCAN_BLOCK 1024
#define N_SCAN_BLOCKS ((N_NODES + SCAN_BLOCK - 1) / SCAN_BLOCK)  // 49
#define NPART 8
#define PART_SIZE ((N_NODES + NPART - 1) / NPART)  // 6250
#define SCATTER_BLOCKS 2048                        // 256 blocks per partition

// ws layout (int units):
//   cnt   [0, N)          per-dst edge count (histogram)
//   excl  [N, 2N)         per-block exclusive scan of cnt
//   bsum  [2N, 2N+64)
//   bsumx [2N+64, 2N+128)
//   rank  [2N+128, 2N+128+E)       rank of edge within its dst bin
//   pair  [2N+128+E, 2N+128+3E)    int2 {e, src[e]} sorted by dst (12.8 MB)
#define WS_CNT   0
#define WS_EXCL  (N_NODES)
#define WS_BSUM  (2 * N_NODES)
#define WS_BSUMX (2 * N_NODES + 64)
#define WS_RANK  (2 * N_NODES + 128)
#define WS_PAIR  (2 * N_NODES + 128 + N_EDGES)

typedef float f4 __attribute__((ext_vector_type(4)));

// -------- main path --------

// rank[e] = old count of dst[e]; cnt accumulates histogram.
// int4-vectorized: 4 edges/thread, 4 independent atomics, coalesced int4 rank store.
__global__ void hist_rank(const int* __restrict__ dst,
                          int* __restrict__ cnt,
                          int* __restrict__ rank) {
    int q = blockIdx.x * blockDim.x + threadIdx.x;
    const int NQ = N_EDGES / 4;
    if (q >= NQ) return;
    int4 d4 = ((const int4*)dst)[q];
    int4 r4;
    r4.x = atomicAdd(&cnt[d4.x], 1);
    r4.y = atomicAdd(&cnt[d4.y], 1);
    r4.z = atomicAdd(&cnt[d4.z], 1);
    r4.w = atomicAdd(&cnt[d4.w], 1);
    ((int4*)rank)[q] = r4;
}

__global__ void scan_blocks(const int* __restrict__ cnt,
                            int* __restrict__ excl,
                            int* __restrict__ bsum) {
    __shared__ int lds[SCAN_BLOCK];
    int tid = threadIdx.x;
    int i = blockIdx.x * SCAN_BLOCK + tid;
    int v = (i < N_NODES) ? cnt[i] : 0;
    int sum = v;
    lds[tid] = v;
    __syncthreads();
    for (int ofs = 1; ofs < SCAN_BLOCK; ofs <<= 1) {
        int t = (tid >= ofs) ? lds[tid - ofs] : 0;
        __syncthreads();
        sum += t;
        lds[tid] = sum;
        __syncthreads();
    }
    if (i < N_NODES) excl[i] = sum - v;
    if (tid == SCAN_BLOCK - 1) bsum[blockIdx.x] = lds[SCAN_BLOCK - 1];
}

// one wave: shuffle-based exclusive scan of the 49 block sums
__global__ void scan_bsums(const int* __restrict__ bsum, int* __restrict__ bsumx) {
    int lane = threadIdx.x;
    int orig = (lane < N_SCAN_BLOCKS) ? bsum[lane] : 0;
    int v = orig;
    for (int o = 1; o < 64; o <<= 1) {
        int t = __shfl_up(v, o);
        if (lane >= o) v += t;
    }
    if (lane < N_SCAN_BLOCKS) bsumx[lane] = v - orig;
}

// XCD-partitioned, rank-based (atomic-free) scatter.
// Block b handles only dsts in [(b&7)*PART_SIZE, +PART_SIZE); partition p's
// pair[] slice (~1.6 MB, contiguous) is then written only by XCD p (round-robin
// blockIdx->XCD mapping), so 64B sectors accumulate all ~8 records in one L2
// before a single writeback (~102 MB -> ~13 MB effective write traffic).
// Redundant dst reads (8x, 51 MB) are L3-absorbed; src/rank loaded only when
// the quad has a match. No atomics anywhere in the store path.
__global__ void scatter_pairs(const int* __restrict__ src,
                              const int* __restrict__ dst,
                              const int* __restrict__ excl,
                              const int* __restrict__ bsumx,
                              const int* __restrict__ rank,
                              int2* __restrict__ pair) {
    int part = blockIdx.x & (NPART - 1);
    int lo = part * PART_SIZE;
    int bi = blockIdx.x >> 3;
    const int nb = SCATTER_BLOCKS / NPART;  // 256 blocks per partition
    const int NQ = N_EDGES / 4;
    for (int q = bi * blockDim.x + threadIdx.x; q < NQ; q += nb * blockDim.x) {
        int4 d4 = ((const int4*)dst)[q];
        bool ax = (unsigned)(d4.x - lo) < (unsigned)PART_SIZE;
        bool ay = (unsigned)(d4.y - lo) < (unsigned)PART_SIZE;
        bool az = (unsigned)(d4.z - lo) < (unsigned)PART_SIZE;
        bool aw = (unsigned)(d4.w - lo) < (unsigned)PART_SIZE;
        if (!(ax | ay | az | aw)) continue;
        int4 s4 = ((const int4*)src)[q];
        int4 r4 = ((const int4*)rank)[q];
        int e0 = q * 4;
        if (ax) pair[excl[d4.x] + bsumx[d4.x >> 10] + r4.x] = make_int2(e0,     s4.x);
        if (ay) pair[excl[d4.y] + bsumx[d4.y >> 10] + r4.y] = make_int2(e0 + 1, s4.y);
        if (az) pair[excl[d4.z] + bsumx[d4.z >> 10] + r4.z] = make_int2(e0 + 2, s4.z);
        if (aw) pair[excl[d4.w] + bsumx[d4.w >> 10] + r4.w] = make_int2(e0 + 3, s4.w);
    }
}

// per (node, float4-group): walk the node's contiguous pair records, gather
// edge_feat/node_feat rows, relu-sum on the fly, add eps-scaled residual.
// 8-lane groups broadcast pair records via shfl; main loop fully unrolled.
__global__ void reduce_gather(const float* __restrict__ node_feat,
                              const float* __restrict__ edge_feat,
                              const float* __restrict__ eps,
                              const int* __restrict__ excl,
                              const int* __restrict__ bsumx,
                              const int* __restrict__ cnt,
                              const int2* __restrict__ pair,
                              float* __restrict__ out) {
    int t = blockIdx.x * blockDim.x + threadIdx.x;
    int n = t >> 3;
    int g = t & 7;
    if (n >= N_NODES) return;

    int start = excl[n] + bsumx[n >> 10];
    int c = cnt[n];
    int gbase = (threadIdx.x & 63) & ~7;  // base lane of this 8-lane group

    const f4* efp = (const f4*)edge_feat;
    const f4* nfp = (const f4*)node_feat;

    f4 acc = (f4)(0.f);
    int i0 = 0;
    for (; i0 + 8 <= c; i0 += 8) {
        int2 p = pair[start + i0 + g];  // 8 lanes x 8B = 64B coalesced
#pragma unroll
        for (int j = 0; j < 8; ++j) {
            int e = __shfl(p.x, gbase + j);
            int s = __shfl(p.y, gbase + j);
            f4 ef = __builtin_nontemporal_load(&efp[(size_t)e * 8 + g]);
            f4 nf = nfp[(size_t)s * 8 + g];
            acc.x += fmaxf(nf.x + ef.x, 0.f);
            acc.y += fmaxf(nf.y + ef.y, 0.f);
            acc.z += fmaxf(nf.z + ef.z, 0.f);
            acc.w += fmaxf(nf.w + ef.w, 0.f);
        }
    }
    int rem = c - i0;
    if (rem > 0) {
        int2 p = (g < rem) ? pair[start + i0 + g] : make_int2(0, 0);
        for (int j = 0; j < rem; ++j) {
            int e = __shfl(p.x, gbase + j);
            int s = __shfl(p.y, gbase + j);
            f4 ef = __builtin_nontemporal_load(&efp[(size_t)e * 8 + g]);
            f4 nf = nfp[(size_t)s * 8 + g];
            acc.x += fmaxf(nf.x + ef.x, 0.f);
            acc.y += fmaxf(nf.y + ef.y, 0.f);
            acc.z += fmaxf(nf.z + ef.z, 0.f);
            acc.w += fmaxf(nf.w + ef.w, 0.f);
        }
    }

    float scale = 1.0f + eps[0];
    f4 h = nfp[(size_t)n * 8 + g];
    f4 o;
    o.x = scale * h.x + acc.x;
    o.y = scale * h.y + acc.y;
    o.z = scale * h.z + acc.z;
    o.w = scale * h.w + acc.w;
    ((f4*)out)[(size_t)n * 8 + g] = o;
}

// -------- fallback path (tiny ws): direct atomics --------

__global__ void fb_init_out(const float* __restrict__ node_feat,
                            const float* __restrict__ eps,
                            float* __restrict__ out) {
    int i = blockIdx.x * blockDim.x + threadIdx.x;
    const int n4 = N_NODES * D_FEAT / 4;
    float scale = 1.0f + eps[0];
    if (i < n4) {
        float4 v = ((const float4*)node_feat)[i];
        v.x *= scale; v.y *= scale; v.z *= scale; v.w *= scale;
        ((float4*)out)[i] = v;
    }
}

__global__ void fb_scatter(const float* __restrict__ node_feat,
                           const float* __restrict__ edge_feat,
                           const int* __restrict__ src,
                           const int* __restrict__ dst,
                           float* __restrict__ out) {
    int t = blockIdx.x * blockDim.x + threadIdx.x;
    int e = t >> 3;
    int g = t & 7;
    if (e >= N_EDGES) return;
    int s = src[e];
    int d = dst[e];
    float4 nf = ((const float4*)node_feat)[s * 8 + g];
    float4 ef = ((const float4*)edge_feat)[(size_t)e * 8 + g];
    float* op = out + (size_t)d * D_FEAT + g * 4;
    unsafeAtomicAdd(op + 0, fmaxf(nf.x + ef.x, 0.f));
    unsafeAtomicAdd(op + 1, fmaxf(nf.y + ef.y, 0.f));
    unsafeAtomicAdd(op + 2, fmaxf(nf.z + ef.z, 0.f));
    unsafeAtomicAdd(op + 3, fmaxf(nf.w + ef.w, 0.f));
}

extern "C" void kernel_launch(void* const* d_in, const int* in_sizes, int n_in,
                              void* d_out, int out_size, void* d_ws, size_t ws_size,
                              hipStream_t stream) {
    const float* node_feat = (const float*)d_in[0];
    const float* edge_feat = (const float*)d_in[1];
    const float* eps       = (const float*)d_in[2];
    const int*   src       = (const int*)d_in[3];
    const int*   dst       = (const int*)d_in[4];
    float* out = (float*)d_out;

    const int B = 256;
    const size_t need = ((size_t)WS_PAIR + 2ull * N_EDGES) * sizeof(int);

    if (ws_size < need) {
        // fallback: direct fp32 atomics (no ws)
        int n4 = N_NODES * D_FEAT / 4;
        fb_init_out<<<(n4 + B - 1) / B, B, 0, stream>>>(node_feat, eps, out);
        long long total = (long long)N_EDGES * 8;
        fb_scatter<<<(int)((total + B - 1) / B), B, 0, stream>>>(
            node_feat, edge_feat, src, dst, out);
        return;
    }

    int* ws = (int*)d_ws;
    int*  cnt   = ws + WS_CNT;
    int*  excl  = ws + WS_EXCL;
    int*  bsum  = ws + WS_BSUM;
    int*  bsumx = ws + WS_BSUMX;
    int*  rank  = ws + WS_RANK;
    int2* pair  = (int2*)(ws + WS_PAIR);

    hipMemsetAsync(cnt, 0, N_NODES * sizeof(int), stream);

    int nq = N_EDGES / 4;
    hist_rank<<<(nq + B - 1) / B, B, 0, stream>>>(dst, cnt, rank);
    scan_blocks<<<N_SCAN_BLOCKS, SCAN_BLOCK, 0, stream>>>(cnt, excl, bsum);
    scan_bsums<<<1, 64, 0, stream>>>(bsum, bsumx);

    scatter_pairs<<<SCATTER_BLOCKS, B, 0, stream>>>(
        src, dst, excl, bsumx, rank, pair);

    long long ntotal = (long long)N_NODES * 8;
    reduce_gather<<<(int)((ntotal + B - 1) / B), B, 0, stream>>>(
        node_feat, edge_feat, eps, excl, bsumx, cnt, pair, out);
}

// Round 6
// 427.091 us; speedup vs baseline: 1.0241x; 1.0241x over previous
//
#include <hip/hip_runtime.h>

#define N_NODES 50000
#define N_EDGES 1600000
#define D_FEAT 32
#define SCAN_BLOCK 1024
#define N_SCAN_BLOCKS ((N_NODES + SCAN_BLOCK - 1) / SCAN_BLOCK)  // 49
#define CHUNK 64
#define NCHUNK (N_EDGES / CHUNK)  // 25000, exact

// ws layout (int units):
//   cnt   [0, N)            per-dst edge count (histogram)
//   excl  [N, 2N)           per-block exclusive scan of cnt
//   off   [2N, 3N+1)        global exclusive offsets, off[N] = E sentinel
//   bsum  [3N+64, 3N+128)
//   bsumx [3N+128, 3N+192)
//   rank  [3N+192, 3N+192+E)       rank of edge within its dst bin
//   pair  [3N+192+E, 3N+192+3E)    int2 {e, src[e]} sorted by dst (12.8 MB)
#define WS_CNT   0
#define WS_EXCL  (N_NODES)
#define WS_OFF   (2 * N_NODES)
#define WS_BSUM  (3 * N_NODES + 64)
#define WS_BSUMX (3 * N_NODES + 128)
#define WS_RANK  (3 * N_NODES + 192)
#define WS_PAIR  (3 * N_NODES + 192 + N_EDGES)

typedef float f4 __attribute__((ext_vector_type(4)));

// -------- main path --------

// rank[e] = old count of dst[e]; cnt accumulates histogram.
// int4-vectorized: 4 edges/thread, 4 independent atomics, coalesced int4 rank store.
__global__ void hist_rank(const int* __restrict__ dst,
                          int* __restrict__ cnt,
                          int* __restrict__ rank) {
    int q = blockIdx.x * blockDim.x + threadIdx.x;
    const int NQ = N_EDGES / 4;
    if (q >= NQ) return;
    int4 d4 = ((const int4*)dst)[q];
    int4 r4;
    r4.x = atomicAdd(&cnt[d4.x], 1);
    r4.y = atomicAdd(&cnt[d4.y], 1);
    r4.z = atomicAdd(&cnt[d4.z], 1);
    r4.w = atomicAdd(&cnt[d4.w], 1);
    ((int4*)rank)[q] = r4;
}

__global__ void scan_blocks(const int* __restrict__ cnt,
                            int* __restrict__ excl,
                            int* __restrict__ bsum) {
    __shared__ int lds[SCAN_BLOCK];
    int tid = threadIdx.x;
    int i = blockIdx.x * SCAN_BLOCK + tid;
    int v = (i < N_NODES) ? cnt[i] : 0;
    int sum = v;
    lds[tid] = v;
    __syncthreads();
    for (int ofs = 1; ofs < SCAN_BLOCK; ofs <<= 1) {
        int t = (tid >= ofs) ? lds[tid - ofs] : 0;
        __syncthreads();
        sum += t;
        lds[tid] = sum;
        __syncthreads();
    }
    if (i < N_NODES) excl[i] = sum - v;
    if (tid == SCAN_BLOCK - 1) bsum[blockIdx.x] = lds[SCAN_BLOCK - 1];
}

// one wave: shuffle-based exclusive scan of the 49 block sums
__global__ void scan_bsums(const int* __restrict__ bsum, int* __restrict__ bsumx) {
    int lane = threadIdx.x;
    int orig = (lane < N_SCAN_BLOCKS) ? bsum[lane] : 0;
    int v = orig;
    for (int o = 1; o < 64; o <<= 1) {
        int t = __shfl_up(v, o);
        if (lane >= o) v += t;
    }
    if (lane < N_SCAN_BLOCKS) bsumx[lane] = v - orig;
}

// off[i] = global exclusive offset; off[N] = E sentinel (dense segments:
// off[n+1] - off[n] = cnt[n], so reduce needs only off).
__global__ void finalize_off(const int* __restrict__ excl,
                             const int* __restrict__ bsumx,
                             int* __restrict__ off) {
    int i = blockIdx.x * SCAN_BLOCK + threadIdx.x;
    if (i < N_NODES) off[i] = excl[i] + bsumx[blockIdx.x];
    else if (i == N_NODES) off[i] = N_EDGES;
}

// R4-proven scatter: rank-based, atomic-free store path, 4 edges/thread,
// int4 reads; position via materialized off (one L2 load per edge).
__global__ void scatter_pairs(const int* __restrict__ src,
                              const int* __restrict__ dst,
                              const int* __restrict__ off,
                              const int* __restrict__ rank,
                              int2* __restrict__ pair) {
    int q = blockIdx.x * blockDim.x + threadIdx.x;
    const int NQ = N_EDGES / 4;
    if (q >= NQ) return;
    int4 d4 = ((const int4*)dst)[q];
    int4 s4 = ((const int4*)src)[q];
    int4 r4 = ((const int4*)rank)[q];
    int e0 = q * 4;
    pair[off[d4.x] + r4.x] = make_int2(e0,     s4.x);
    pair[off[d4.y] + r4.y] = make_int2(e0 + 1, s4.y);
    pair[off[d4.z] + r4.z] = make_int2(e0 + 2, s4.z);
    pair[off[d4.w] + r4.w] = make_int2(e0 + 3, s4.w);
}

// out = (1+eps) * node_feat  (residual pre-init; reduce_chunks atomically
// accumulates messages on top)
__global__ void init_out(const float* __restrict__ node_feat,
                         const float* __restrict__ eps,
                         float* __restrict__ out) {
    int i = blockIdx.x * blockDim.x + threadIdx.x;
    const int n4 = N_NODES * D_FEAT / 4;
    float scale = 1.0f + eps[0];
    if (i < n4) {
        float4 v = ((const float4*)node_feat)[i];
        v.x *= scale; v.y *= scale; v.z *= scale; v.w *= scale;
        ((float4*)out)[i] = v;
    }
}

// Edge-parallel, perfectly load-balanced reduce: each 8-lane group owns one
// chunk of 64 consecutive dst-sorted pair slots (every wave = exactly 512
// edges). Segment containing the chunk start found by binary search on off
// (L2-hot); boundaries walked inline; partial sums flushed to out via
// unsafeAtomicAdd (8 lanes x 16B = full 128B row per flush, no sector amp;
// ~75k flushes total). Control flow uniform within each group.
__global__ void reduce_chunks(const float* __restrict__ node_feat,
                              const float* __restrict__ edge_feat,
                              const int* __restrict__ off,
                              const int2* __restrict__ pair,
                              float* __restrict__ out) {
    int t = blockIdx.x * blockDim.x + threadIdx.x;
    int grp = t >> 3;
    int g = t & 7;
    if (grp >= NCHUNK) return;
    int p0 = grp * CHUNK;
    int gbase = (threadIdx.x & 63) & ~7;  // base lane of this 8-lane group

    // largest n with off[n] <= p0 (off[n+1] > p0 by construction)
    int lo = 0, hi = N_NODES - 1;
    while (lo < hi) {
        int mid = (lo + hi + 1) >> 1;
        if (off[mid] <= p0) lo = mid; else hi = mid - 1;
    }
    int n = lo;
    int segEnd = off[n + 1];

    const f4* efp = (const f4*)edge_feat;
    const f4* nfp = (const f4*)node_feat;

    f4 acc = (f4)(0.f);
    for (int k = 0; k < CHUNK; k += 8) {
        int2 p = pair[p0 + k + g];  // 8 lanes x 8B = 64B coalesced
#pragma unroll
        for (int j = 0; j < 8; ++j) {
            int pos = p0 + k + j;
            while (pos == segEnd) {  // segment boundary: flush + advance
                float* op = out + (size_t)n * D_FEAT + g * 4;
                unsafeAtomicAdd(op + 0, acc.x);
                unsafeAtomicAdd(op + 1, acc.y);
                unsafeAtomicAdd(op + 2, acc.z);
                unsafeAtomicAdd(op + 3, acc.w);
                acc = (f4)(0.f);
                ++n;
                segEnd = off[n + 1];
            }
            int e = __shfl(p.x, gbase + j);
            int s = __shfl(p.y, gbase + j);
            f4 ef = __builtin_nontemporal_load(&efp[(size_t)e * 8 + g]);
            f4 nf = nfp[(size_t)s * 8 + g];
            acc.x += fmaxf(nf.x + ef.x, 0.f);
            acc.y += fmaxf(nf.y + ef.y, 0.f);
            acc.z += fmaxf(nf.z + ef.z, 0.f);
            acc.w += fmaxf(nf.w + ef.w, 0.f);
        }
    }
    // final (possibly partial) segment flush
    float* op = out + (size_t)n * D_FEAT + g * 4;
    unsafeAtomicAdd(op + 0, acc.x);
    unsafeAtomicAdd(op + 1, acc.y);
    unsafeAtomicAdd(op + 2, acc.z);
    unsafeAtomicAdd(op + 3, acc.w);
}

// -------- fallback path (tiny ws): direct atomics --------

__global__ void fb_scatter(const float* __restrict__ node_feat,
                           const float* __restrict__ edge_feat,
                           const int* __restrict__ src,
                           const int* __restrict__ dst,
                           float* __restrict__ out) {
    int t = blockIdx.x * blockDim.x + threadIdx.x;
    int e = t >> 3;
    int g = t & 7;
    if (e >= N_EDGES) return;
    int s = src[e];
    int d = dst[e];
    float4 nf = ((const float4*)node_feat)[s * 8 + g];
    float4 ef = ((const float4*)edge_feat)[(size_t)e * 8 + g];
    float* op = out + (size_t)d * D_FEAT + g * 4;
    unsafeAtomicAdd(op + 0, fmaxf(nf.x + ef.x, 0.f));
    unsafeAtomicAdd(op + 1, fmaxf(nf.y + ef.y, 0.f));
    unsafeAtomicAdd(op + 2, fmaxf(nf.z + ef.z, 0.f));
    unsafeAtomicAdd(op + 3, fmaxf(nf.w + ef.w, 0.f));
}

extern "C" void kernel_launch(void* const* d_in, const int* in_sizes, int n_in,
                              void* d_out, int out_size, void* d_ws, size_t ws_size,
                              hipStream_t stream) {
    const float* node_feat = (const float*)d_in[0];
    const float* edge_feat = (const float*)d_in[1];
    const float* eps       = (const float*)d_in[2];
    const int*   src       = (const int*)d_in[3];
    const int*   dst       = (const int*)d_in[4];
    float* out = (float*)d_out;

    const int B = 256;
    const size_t need = ((size_t)WS_PAIR + 2ull * N_EDGES) * sizeof(int);

    if (ws_size < need) {
        // fallback: direct fp32 atomics (no ws)
        int n4 = N_NODES * D_FEAT / 4;
        init_out<<<(n4 + B - 1) / B, B, 0, stream>>>(node_feat, eps, out);
        long long total = (long long)N_EDGES * 8;
        fb_scatter<<<(int)((total + B - 1) / B), B, 0, stream>>>(
            node_feat, edge_feat, src, dst, out);
        return;
    }

    int* ws = (int*)d_ws;
    int*  cnt   = ws + WS_CNT;
    int*  excl  = ws + WS_EXCL;
    int*  off   = ws + WS_OFF;
    int*  bsum  = ws + WS_BSUM;
    int*  bsumx = ws + WS_BSUMX;
    int*  rank  = ws + WS_RANK;
    int2* pair  = (int2*)(ws + WS_PAIR);

    hipMemsetAsync(cnt, 0, N_NODES * sizeof(int), stream);

    int nq = N_EDGES / 4;
    hist_rank<<<(nq + B - 1) / B, B, 0, stream>>>(dst, cnt, rank);
    scan_blocks<<<N_SCAN_BLOCKS, SCAN_BLOCK, 0, stream>>>(cnt, excl, bsum);
    scan_bsums<<<1, 64, 0, stream>>>(bsum, bsumx);
    finalize_off<<<N_SCAN_BLOCKS, SCAN_BLOCK, 0, stream>>>(excl, bsumx, off);

    scatter_pairs<<<(nq + B - 1) / B, B, 0, stream>>>(src, dst, off, rank, pair);

    int n4 = N_NODES * D_FEAT / 4;
    init_out<<<(n4 + B - 1) / B, B, 0, stream>>>(node_feat, eps, out);

    long long rtotal = (long long)NCHUNK * 8;
    reduce_chunks<<<(int)((rtotal + B - 1) / B), B, 0, stream>>>(
        node_feat, edge_feat, off, pair, out);
}